// Round 3
// baseline (394.486 us; speedup 1.0000x reference)
//
#include <hip/hip_runtime.h>

#define BATCH 131072

typedef __attribute__((ext_vector_type(8))) __bf16 bf16x8;
typedef __attribute__((ext_vector_type(16))) float f32x16;

__constant__ int FOFF[23] = {0,4,8,12,16,20,24,28,32,36,40,44,48,50,52,53,57,58,59,60,61,62,63};
__constant__ int FDIM[23] = {4,4,4,4,4,4,4,4,4,4,4,4,2,2,1,4,1,1,1,1,1,1,2};

__device__ __forceinline__ unsigned short f2bf(float f){
  unsigned int u = __float_as_uint(f);
  u += 0x7fffu + ((u>>16)&1u);   // RNE
  return (unsigned short)(u>>16);
}
__device__ __forceinline__ unsigned int packpair(float a, float b){
  return (unsigned int)f2bf(a) | ((unsigned int)f2bf(b)<<16);
}
__device__ __forceinline__ float bflo(unsigned int u){ return __uint_as_float(u<<16); }
__device__ __forceinline__ float bfhi(unsigned int u){ return __uint_as_float(u & 0xffff0000u); }

// ---------------- prep: pack W1..W5 into MFMA-B fragment-linear bf16 layout ----------------
__global__ void prep_weights(const float* __restrict__ W1, const float* __restrict__ W2,
    const float* __restrict__ W3, const float* __restrict__ W4, const float* __restrict__ W5,
    unsigned short* __restrict__ wpack){
  int idx = blockIdx.x*256 + threadIdx.x;
  if (idx >= 22656) return;
  const float* W; int rel; int Kd;
  if (idx < 5760){ W = W1; rel = idx; Kd = 230; }
  else {
    int r2 = idx - 5760;
    int li = r2 / 4224; rel = r2 - li*4224; Kd = 164;
    W = (li==0)?W2:((li==1)?W3:((li==2)?W4:W5));
  }
  int lane = rel & 63, rem = rel >> 6;
  int nt = rem % 6, ks = rem / 6;
  int n  = nt*32 + (lane&31);
  int k0 = ks*16 + ((lane>>5)<<3);
  unsigned int v[4];
  #pragma unroll
  for (int p=0;p<4;p++){
    int ka = k0 + 2*p, kb = ka+1;
    float fa = (ka<Kd && n<164) ? W[ka*164+n] : 0.f;
    float fb = (kb<Kd && n<164) ? W[kb*164+n] : 0.f;
    v[p] = packpair(fa, fb);
  }
  *(uint4*)(wpack + (size_t)idx*8) = make_uint4(v[0],v[1],v[2],v[3]);
}

// ---------------- attention: 3 query rows of one sample (8 threads/sample) ----------------
// h layout: hp[s*140 + j*6 + p], p=0..4 are bf16 pairs (token row padded to 24 B).
__device__ __forceinline__ void attn3(int s, int q,
    const unsigned int* hp, const float* sw, unsigned int* z32){
  const int i0 = 3*q;
  const bool have2 = (q < 7);          // q==7 owns only rows 21,22
  const unsigned int* hrow = hp + s*140;

  // ---- g[c] = h_{i0+c} * M ----
  float g[3][10];
  #pragma unroll
  for (int c=0;c<3;c++)
    #pragma unroll
    for (int d=0;d<10;d++) g[c][d]=0.f;
  {
    float hi[3][10];
    #pragma unroll
    for (int c=0;c<3;c++){
      if (c<2 || have2){
        const uint2* kb = (const uint2*)(hrow + (i0+c)*6);
        uint2 u01 = kb[0], u23 = kb[1], u4x = kb[2];
        hi[c][0]=bflo(u01.x); hi[c][1]=bfhi(u01.x);
        hi[c][2]=bflo(u01.y); hi[c][3]=bfhi(u01.y);
        hi[c][4]=bflo(u23.x); hi[c][5]=bfhi(u23.x);
        hi[c][6]=bflo(u23.y); hi[c][7]=bfhi(u23.y);
        hi[c][8]=bflo(u4x.x); hi[c][9]=bfhi(u4x.x);
      } else {
        #pragma unroll
        for (int d=0;d<10;d++) hi[c][d]=0.f;
      }
    }
    #pragma unroll
    for (int e=0;e<10;e++){
      const float4* mr = (const float4*)(sw + 1840 + e*12);
      float4 m0 = mr[0], m1 = mr[1];
      float2 m2 = *(const float2*)(sw + 1840 + e*12 + 8);
      float m[10] = {m0.x,m0.y,m0.z,m0.w, m1.x,m1.y,m1.z,m1.w, m2.x,m2.y};
      #pragma unroll
      for (int c=0;c<3;c++){
        float he = hi[c][e];
        #pragma unroll
        for (int d=0;d<10;d++) g[c][d] += he*m[d];
      }
    }
  }

  // ---- single-pass unnormalized softmax over 23 keys ----
  float st[3][10]; float tau[3];
  #pragma unroll
  for (int c=0;c<3;c++){
    tau[c]=0.f;
    #pragma unroll
    for (int d=0;d<10;d++) st[c][d]=0.f;
  }
  for (int j=0;j<23;j++){
    const uint2* kb = (const uint2*)(hrow + j*6);
    uint2 u01 = kb[0], u23 = kb[1], u4x = kb[2];
    float hj[10];
    hj[0]=bflo(u01.x); hj[1]=bfhi(u01.x);
    hj[2]=bflo(u01.y); hj[3]=bfhi(u01.y);
    hj[4]=bflo(u23.x); hj[5]=bfhi(u23.x);
    hj[6]=bflo(u23.y); hj[7]=bfhi(u23.y);
    hj[8]=bflo(u4x.x); hj[9]=bfhi(u4x.x);
    #pragma unroll
    for (int c=0;c<3;c++){
      float l = 0.f;
      #pragma unroll
      for (int d=0;d<10;d++) l += g[c][d]*hj[d];
      float e = __expf(l);
      tau[c] += e;
      #pragma unroll
      for (int d=0;d<10;d++) st[c][d] += e*hj[d];
    }
  }
  #pragma unroll
  for (int c=0;c<3;c++){
    float inv = __builtin_amdgcn_rcpf(tau[c]);
    #pragma unroll
    for (int d=0;d<10;d++) st[c][d] *= inv;
  }

  // ---- ctx = st * Wv ----
  float ct[3][10];
  #pragma unroll
  for (int c=0;c<3;c++)
    #pragma unroll
    for (int d=0;d<10;d++) ct[c][d]=0.f;
  #pragma unroll
  for (int e=0;e<10;e++){
    const float4* wr = (const float4*)(sw + 1960 + e*12);
    float4 w0 = wr[0], w1 = wr[1];
    float2 w2 = *(const float2*)(sw + 1960 + e*12 + 8);
    float wv[10] = {w0.x,w0.y,w0.z,w0.w, w1.x,w1.y,w1.z,w1.w, w2.x,w2.y};
    #pragma unroll
    for (int c=0;c<3;c++){
      float se = st[c][e];
      #pragma unroll
      for (int d=0;d<10;d++) ct[c][d] += se*wv[d];
    }
  }

  // ---- residual + pack to z (guarded) ----
  #pragma unroll
  for (int c=0;c<3;c++){
    if (c<2 || have2){
      int i = i0+c;
      #pragma unroll
      for (int p=0;p<5;p++){
        unsigned int u = hrow[i*6 + p];
        float z0 = bflo(u) + ct[c][2*p];
        float z1 = bfhi(u) + ct[c][2*p+1];
        z32[s*124 + i*5 + p] = packpair(z0,z1);
      }
    }
  }
}

// ---------------- MFMA MLP layer: [128,K]x[K,192] -> relu -> act (pitch 200) ----------------
// 16 waves: 24 wave-tiles (4M x 6N). Waves 0-7: 2 N-tiles (same mt), waves 8-15: 1.
template<int KSTEPS>
__device__ __forceinline__ void mlp_layer(const unsigned short* in16, int inPitch,
    const bf16x8* __restrict__ wp, const float* __restrict__ bias,
    unsigned short* out16, int t){
  const int lane = t & 63;
  const int w = t >> 6;            // 0..15
  const int mt = w & 3;
  const bool two = (w < 8);
  const int nt0 = two ? (w>>2) : (2 + ((w>>2)&1));
  const int nt1 = nt0 + 4;         // only used when two
  f32x16 acc0, acc1;
  #pragma unroll
  for (int r=0;r<16;r++){ acc0[r]=0.f; acc1[r]=0.f; }
  const unsigned short* abase = in16 + (mt*32 + (lane&31))*inPitch + ((lane>>5)<<3);
  const bf16x8* wb = wp + lane;
  #pragma unroll
  for (int ks=0; ks<KSTEPS; ++ks){
    bf16x8 a = *(const bf16x8*)(abase + ks*16);
    acc0 = __builtin_amdgcn_mfma_f32_32x32x16_bf16(a, wb[(ks*6+nt0)*64], acc0, 0,0,0);
    if (two)
      acc1 = __builtin_amdgcn_mfma_f32_32x32x16_bf16(a, wb[(ks*6+nt1)*64], acc1, 0,0,0);
  }
  const int colb = (lane&31);
  const int rowb = mt*32 + 4*(lane>>5);
  #pragma unroll
  for (int sel=0; sel<2; ++sel){
    if (sel==1 && !two) break;
    int nt = (sel==0)? nt0 : nt1;
    int n = nt*32 + colb;
    float b = (n<164) ? bias[n] : 0.f;
    f32x16 acc = (sel==0)? acc0 : acc1;
    #pragma unroll
    for (int r=0;r<16;r++){
      int row = rowb + (r&3) + 8*(r>>2);
      float v = fmaxf(acc[r] + b, 0.f);
      out16[row*200 + n] = f2bf(v);
    }
  }
}

// ---------------- fused main kernel: 128 samples / workgroup, 1024 threads ----------------
__global__ __launch_bounds__(1024, 4) void actor_main(
    const float* __restrict__ xg, const float* __restrict__ Wproj, const float* __restrict__ bproj,
    const float* __restrict__ Wq, const float* __restrict__ Wk, const float* __restrict__ Wv,
    const float* __restrict__ b1, const float* __restrict__ b2, const float* __restrict__ b3,
    const float* __restrict__ b4, const float* __restrict__ b5,
    const float* __restrict__ Wmove, const float* __restrict__ bmove,
    const float* __restrict__ Wmark, const float* __restrict__ bmark,
    const unsigned short* __restrict__ wpack, float* __restrict__ out)
{
  // LDS: [0,63488) z-buffer (pitch 124 u32) / x-stage union;
  //      [63488,135168) h sample-major (140 u32/sample) / MLP act buffer (pitch 200 bf16);
  //      [135168,145456) small weights
  __shared__ __align__(16) unsigned char LDS[145456];
  float* xb = (float*)LDS;
  unsigned int* z32 = (unsigned int*)LDS;
  unsigned short* z16 = (unsigned short*)LDS;
  unsigned int* hp = (unsigned int*)(LDS + 63488);
  unsigned short* a16 = (unsigned short*)(LDS + 63488);
  float* sw = (float*)(LDS + 135168);
  unsigned int* swu = (unsigned int*)(LDS + 135168);

  const int t = threadIdx.x;
  const int S0 = blockIdx.x*128;

  // ---- P0: stage x (float4-coalesced) + pad + small weights ----
  {
    const uint4* src4 = (const uint4*)(xg + (size_t)S0*65);
    uint4* dst4 = (uint4*)xb;
    for (int i=t; i<2080; i+=1024) dst4[i] = src4[i];
    if (t<8) xb[8320+t] = 0.f;
  }
  for (int idx=t; idx<2572; idx+=1024){
    if (idx < 1840){                 // proj packed: [o][0..3]=w, [4]=bias
      int o = idx>>3, u = idx&7;
      int fi = o/10;
      float v = 0.f;
      if (u<4){ if (u < FDIM[fi]) v = Wproj[(FOFF[fi]+u)*230 + o]; }
      else if (u==4) v = bproj[o];
      sw[idx] = v;
    } else if (idx < 1960){          // M = Wq*Wk^T/sqrt(10), [10][12]
      int r = idx-1840, e = r/12, d = r-12*e;
      float v = 0.f;
      if (d<10){ float ssum=0.f;
        #pragma unroll
        for (int k2=0;k2<10;k2++) ssum += Wq[e*10+k2]*Wk[d*10+k2];
        v = ssum*0.31622776601683794f; }
      sw[idx] = v;
    } else if (idx < 2080){          // Wv [10][12]
      int r = idx-1960, e = r/12, d = r-12*e;
      sw[idx] = (d<10)? Wv[e*10+d] : 0.f;
    } else {                         // head weights, bf16 pairs [6][82]
      int r = idx-2080, o = r/82, kp = r-82*o;
      float w0, w1;
      if (o<5){ w0 = Wmove[(2*kp)*5+o]; w1 = Wmove[(2*kp+1)*5+o]; }
      else    { w0 = Wmark[2*kp];       w1 = Wmark[2*kp+1]; }
      swu[idx] = packpair(w0,w1);
    }
  }
  __syncthreads();

  // ---- P1: block-diagonal projection -> h sample-major bf16 pairs hp[s*140 + j*6 + p] ----
  for (int L=t; L<14720; L+=1024){
    int s = L & 127, jp = L>>7;
    int j = jp/5, p = jp-5*j;
    int o0 = j*10 + 2*p;
    int roff = FOFF[j];
    float a0 = sw[o0*8+4], a1 = sw[o0*8+12];
    #pragma unroll
    for (int u=0;u<4;u++){
      float xv = xb[s*65 + roff + u];
      a0 += xv * sw[o0*8+u];
      a1 += xv * sw[o0*8+8+u];
    }
    hp[s*140 + j*6 + p] = packpair(a0,a1);
  }
  __syncthreads();

  // ---- P2: attention (8 threads/sample, 3 query rows each; q-threads broadcast key reads) ----
  {
    const int q = t & 7;
    const int s = t >> 3;
    attn3(s, q, hp, sw, z32);
    // zero z pad cols 230..239 (K padded to 240 for layer1)
    for (int idx=t; idx<640; idx+=1024){
      int ss = idx/5, pc = idx-5*ss;
      z32[ss*124 + 115+pc] = 0u;
    }
  }
  __syncthreads();

  // ---- P3: MLP, 5 layers of MFMA, ping-pong LDS act buffers ----
  const bf16x8* wpk = (const bf16x8*)wpack;
  mlp_layer<15>(z16, 248, wpk,          b1, a16, t); __syncthreads();
  mlp_layer<11>(a16, 200, wpk + 5760,   b2, z16, t); __syncthreads();
  mlp_layer<11>(z16, 200, wpk + 9984,   b3, a16, t); __syncthreads();
  mlp_layer<11>(a16, 200, wpk + 14208,  b4, z16, t); __syncthreads();
  mlp_layer<11>(z16, 200, wpk + 18432,  b5, a16, t); __syncthreads();

  // ---- P4: heads (move[5] + mark[1]) ----
  if (t < 768){
    int s2 = t & 127, o = t>>7;
    const unsigned int* ar = (const unsigned int*)(a16 + s2*200);
    const unsigned int* wr = swu + 2080 + o*82;
    float acc = 0.f;
    for (int kp=0; kp<82; ++kp){
      unsigned int ua = ar[kp], uw = wr[kp];
      acc += bflo(ua)*bflo(uw) + bfhi(ua)*bfhi(uw);
    }
    acc += (o<5)? bmove[o] : bmark[0];
    if (o<5) out[(size_t)(S0+s2)*5 + o] = acc;
    else     out[(size_t)BATCH*5 + S0 + s2] = acc;
  }
}

extern "C" void kernel_launch(void* const* d_in, const int* in_sizes, int n_in,
                              void* d_out, int out_size, void* d_ws, size_t ws_size,
                              hipStream_t stream){
  (void)in_sizes; (void)n_in; (void)out_size; (void)ws_size;
  const float* x     = (const float*)d_in[0];
  const float* Wproj = (const float*)d_in[1];
  const float* bproj = (const float*)d_in[2];
  const float* Wq    = (const float*)d_in[3];
  const float* Wk    = (const float*)d_in[4];
  const float* Wv    = (const float*)d_in[5];
  const float* W1    = (const float*)d_in[6];
  const float* b1    = (const float*)d_in[7];
  const float* W2    = (const float*)d_in[8];
  const float* b2    = (const float*)d_in[9];
  const float* W3    = (const float*)d_in[10];
  const float* b3    = (const float*)d_in[11];
  const float* W4    = (const float*)d_in[12];
  const float* b4    = (const float*)d_in[13];
  const float* W5    = (const float*)d_in[14];
  const float* b5    = (const float*)d_in[15];
  const float* Wmove = (const float*)d_in[16];
  const float* bmove = (const float*)d_in[17];
  const float* Wmark = (const float*)d_in[18];
  const float* bmark = (const float*)d_in[19];
  unsigned short* wpack = (unsigned short*)d_ws;

  prep_weights<<<89, 256, 0, stream>>>(W1, W2, W3, W4, W5, wpack);
  actor_main<<<1024, 1024, 0, stream>>>(x, Wproj, bproj, Wq, Wk, Wv,
      b1, b2, b3, b4, b5, Wmove, bmove, Wmark, bmark, wpack, (float*)d_out);
}